// Round 9
// baseline (323.059 us; speedup 1.0000x reference)
//
#include <hip/hip_runtime.h>
#include <hip/hip_bf16.h>

// Net_22625887715641: fused conv-feats + channel-normalize + 32x32 normalized
// cross-correlation (23x23 shifts, 362x362 templates).
//
// R19 vs R18 (corr 127.6us, neutral; bank pad hurt, prefetch neutral):
//  Model revision: wall 13k cyc/CU/y is ADDITIVE pipe time — LDS 5.5-6.5k
//  (B reads = 64% of it) + MFMA 3.7k + VALU 1.4k + staging ~1k; R18 proved
//  software prefetch can't create overlap here. Shrink the biggest term:
//  - K-split wave decomposition: group = 6 waves = 3 dy_a-pairs x 2
//    K-halves. Wave (p,kh) computes dy_a in {2p,2p+1} for kt in
//    {3kh..3kh+2}, all 3 nt: one Bf feeds TWO MFMAs -> B LDS reads halve
//    (36.9 -> 18.4 KB/wave/y). A unchanged, MFMA count unchanged, SIMD
//    balance unchanged (12 waves). Both K-half waves atomicAdd partials.
//  - acc[2][3] f32x16 = 96 regs + operands ~24 + addr ~20 = ~150 < 170
//    cap; loads 0-deep (R17 style, proven no-spill), unroll 1 on kt.
//  - revert R18's SB_DYB_B pad (3472 -> 3456): it INCREASED conflicts.
//  - feat/pack/prep unchanged (R18 feat store path kept, neutral).

typedef unsigned short ushort_t;
typedef unsigned int uint_t;
typedef unsigned char uchar_t;
typedef __attribute__((ext_vector_type(4))) float f32x4;
typedef __attribute__((ext_vector_type(16))) float f32x16;
typedef __attribute__((ext_vector_type(4))) uint_t uint4_t;
typedef __attribute__((ext_vector_type(2))) uint_t uint2_t;
typedef __attribute__((ext_vector_type(8))) int int8v;

#define EPSF 2.2204460492503131e-16f
#define X1_N (32*384*384)
#define X2_N (32*32*23*23)

// filtb: fp8 [372 rows][kt64 6][h 2][kg 2][o 32][16B]; row = yf+5
#define FILTB_ROW_B 12288
#define FILTB_BYTES (372*48*32*8)
// prevb: fp8 [32 c][385 rows][432 x]; data rows 0..383 cols 0..383; zeros else
#define PREVB_STRIDE 432
#define PREVB_BYTES (32*385*PREVB_STRIDE)
#define ZERO_BYTES ((size_t)FILTB_BYTES + PREVB_BYTES)
// fT2: fp32 [16 chp][45 rows][12] after prevb
#define FT2_ELEMS (16*45*12)

#define YMAX 367            // y-steps 0..366
#define NCHUNKS 16          // 16 chpairs x 16 chunks = 256 blocks = 1/CU
#define INV_AREA (1.0f/131044.0f)

// One prev y-row image in LDS: [dyb 4][copy 8][432]; copy stride 432
#define SB_COPY_B 432
#define SB_DYB_B  (8*SB_COPY_B)     // 3456 (R18's +16 pad reverted)
#define SB_ROW_B  (4*SB_DYB_B)      // 13824 B per y-row image
#define SB_BYTES  (2*2*SB_ROW_B)    // [group][buf] = 55296 B

// A-ring: 8 slots x one filtb row
#define SA_BYTES  (8*FILTB_ROW_B)   // 98304 B
#define SMEM_TOTAL (SA_BYTES + SB_BYTES)   // 153600 B

// ---------------------------------------------------------------------------
// fp32 -> fp8 e4m3 (OCP), RNE, input assumed in [0, 448).
// ---------------------------------------------------------------------------
__device__ __forceinline__ uint_t f32_to_e4m3(float f) {
  if (f < 0.015625f)                         // subnormal: m * 2^-9
    return (uint_t)__float2int_rn(f * 512.0f);
  uint_t b = __builtin_bit_cast(uint_t, f);
  int e = (int)(b >> 23) - 127;
  uint_t m = b & 0x7FFFFFu;
  uint_t keep = m >> 20;
  uint_t rest = m & 0xFFFFFu;
  keep += (rest > 0x80000u) || (rest == 0x80000u && (keep & 1u));
  if (keep == 8u) { keep = 0u; e += 1; }
  if (e > 8) return 0x7Eu;                   // saturate 448
  return (uint_t)(((e + 7) << 3) | keep);
}

// ---------------------------------------------------------------------------
// Prep: pack filters to [chp][45][12] (rows 16B-aligned, b-contiguous).
// ---------------------------------------------------------------------------
__global__ void prep_kernel(const float* __restrict__ ft, const float* __restrict__ fn,
                            float* __restrict__ fT2)
{
  const int e = blockIdx.x * 256 + threadIdx.x;
  if (e < FT2_ELEMS) {
    const int chp = e / 540;
    const int rem = e - chp * 540;
    const int row = rem / 12;
    const int j = rem - row * 12;
    float v = 0.f;
    if (j < 11) {
      if (row < 33)      v = ft[chp * 363 + row * 11 + j];        // row = t*11+a
      else if (row < 44) v = fn[chp * 121 + (row - 33) * 11 + j]; // row-33 = a
    }
    fT2[e] = v;
  }
}

// ---------------------------------------------------------------------------
// Stage 1: thread = (ch-pair chp) x (16-px row). Block 128 = 8 rows x 16 chp.
// mode 0: x -> x1 (fp32, LDS-transposed coalesced stores).
// mode 1: xprev -> prevb (fp8 e4m3).
// ---------------------------------------------------------------------------
__global__ __launch_bounds__(128, 4) void feat_kernel(
    const float* __restrict__ xcur, const float* __restrict__ xprev,
    const float* __restrict__ fT2,
    float* __restrict__ out_x1, uchar_t* __restrict__ prevb)
{
  __shared__ float sPx[3 * 18 * 28];
  __shared__ float sOut[32][9][20];    // [ch][r pad 9][px pad 20] bank-safe
  const int tid = threadIdx.x;
  const int chp = tid & 15;
  const int r = tid >> 4;              // 0..7
  const int j0 = blockIdx.x * 16;
  const int i0 = blockIdx.y * 8;
  const int i = i0 + r;
  const int mode = blockIdx.z;
  const float* __restrict__ xin = mode ? xprev : xcur;

  for (int e = tid; e < 3 * 18 * 26; e += 128) {
    const int t = e / 468;
    const int rem = e - t * 468;
    const int ri = rem / 26;
    const int ci = rem - ri * 26;
    sPx[(t * 18 + ri) * 28 + ci] = xin[((size_t)t * 394 + i0 + ri) * 394 + j0 + ci];
  }
  __syncthreads();

  const float* __restrict__ fbase = fT2 + chp * 540;

  float accT[16], accN[16];
#pragma unroll
  for (int p = 0; p < 16; ++p) { accT[p] = 0.f; accN[p] = 0.f; }

#pragma unroll
  for (int t = 0; t < 3; ++t) {
    for (int a = 0; a < 11; ++a) {
      const float* row = &sPx[(t * 18 + r + a) * 28];
      float wv[26];
#pragma unroll
      for (int k = 0; k < 6; ++k) {
        const f32x4 q = *(const f32x4*)(row + 4 * k);
        wv[4 * k + 0] = q[0]; wv[4 * k + 1] = q[1];
        wv[4 * k + 2] = q[2]; wv[4 * k + 3] = q[3];
      }
      wv[24] = row[24]; wv[25] = row[25];

      const float* fr = fbase + (t * 11 + a) * 12;
      const f32x4 fq0 = *(const f32x4*)(fr);
      const f32x4 fq1 = *(const f32x4*)(fr + 4);
      const f32x4 fq2 = *(const f32x4*)(fr + 8);
      float fv[12];
#pragma unroll
      for (int k = 0; k < 4; ++k) { fv[k] = fq0[k]; fv[4+k] = fq1[k]; fv[8+k] = fq2[k]; }
      float fv2[12];
      if (t == 2) {
        const float* fr2 = fbase + (33 + a) * 12;
        const f32x4 g0 = *(const f32x4*)(fr2);
        const f32x4 g1 = *(const f32x4*)(fr2 + 4);
        const f32x4 g2 = *(const f32x4*)(fr2 + 8);
#pragma unroll
        for (int k = 0; k < 4; ++k) { fv2[k] = g0[k]; fv2[4+k] = g1[k]; fv2[8+k] = g2[k]; }
      }

#pragma unroll
      for (int b = 0; b < 11; ++b) {
        const float fT = fv[b];
#pragma unroll
        for (int p = 0; p < 16; ++p) accT[p] = fmaf(wv[b + p], fT, accT[p]);
        if (t == 2) {
          const float fN = fv2[b];
#pragma unroll
          for (int p = 0; p < 16; ++p) accN[p] = fmaf(wv[b + p], fN, accN[p]);
        }
      }
    }
  }

  float o0[16], o1[16];
#pragma unroll
  for (int p = 0; p < 16; ++p) {
    const float vT = fmaxf(accT[p], 0.f) * 0.5f;   // temp: relu(conv)/2
    const float vN = fmaxf(accN[p], 0.f);
    float s = vT + vN;
    s += __shfl_xor(s, 1);  s += __shfl_xor(s, 2);
    s += __shfl_xor(s, 4);  s += __shfl_xor(s, 8);
    const float inv = 1.f / (s + EPSF);
    o0[p] = vT * inv;
    o1[p] = vN * inv;
  }

  if (mode == 0) {
    // Stage to LDS, then write 64B-contiguous segments (4 lanes per line).
#pragma unroll
    for (int p = 0; p < 16; ++p) {
      sOut[chp][r][p] = o0[p];
      sOut[chp + 16][r][p] = o1[p];
    }
    __syncthreads();
#pragma unroll
    for (int it = 0; it < 8; ++it) {
      const int idx = it * 128 + tid;        // 0..1023 = 32ch x 8r x 4seg
      const int seg = idx & 3;
      const int rr = (idx >> 2) & 7;
      const int chn = idx >> 5;
      const f32x4 v = {sOut[chn][rr][4 * seg], sOut[chn][rr][4 * seg + 1],
                       sOut[chn][rr][4 * seg + 2], sOut[chn][rr][4 * seg + 3]};
      *(f32x4*)(out_x1 + (size_t)chn * 147456 + (i0 + rr) * 384 + j0 + 4 * seg) = v;
    }
  } else {
    uint4_t u0, u1;
#pragma unroll
    for (int q = 0; q < 4; ++q) {
      u0[q] = f32_to_e4m3(o0[4*q]) | (f32_to_e4m3(o0[4*q+1]) << 8) |
              (f32_to_e4m3(o0[4*q+2]) << 16) | (f32_to_e4m3(o0[4*q+3]) << 24);
      u1[q] = f32_to_e4m3(o1[4*q]) | (f32_to_e4m3(o1[4*q+1]) << 8) |
              (f32_to_e4m3(o1[4*q+2]) << 16) | (f32_to_e4m3(o1[4*q+3]) << 24);
    }
    *(uint4_t*)(prevb + ((size_t)chp * 385 + i) * PREVB_STRIDE + j0) = u0;
    *(uint4_t*)(prevb + ((size_t)(chp + 16) * 385 + i) * PREVB_STRIDE + j0) = u1;
  }
}

// ---------------------------------------------------------------------------
// Pack x1 (fp32, cropped) into filtb fp8 MFMA-A layout; coalesced 8B writes.
// Layout per row: [kt64 6][h 2][kg 2][o 32][16B]; element k = xb*8+j:
// kt64 = xb>>3, kg = (xb>>2)&1, h = (xb>>1)&1, byte16 = (xb&1)*8 + j.
// ---------------------------------------------------------------------------
__global__ __launch_bounds__(256) void pack_kernel(
    const float* __restrict__ x1, uchar_t* __restrict__ filtb)
{
  const int e = blockIdx.x * 256 + threadIdx.x;
  if (e >= 362 * 46 * 32) return;
  const int o = e & 31;
  const int q = e >> 5;
  const int xb = q % 46;
  const int rowr = q / 46 + 5;          // 5..366
  const int i = rowr + 6;               // 11..372
  const int j0 = 11 + xb * 8;
  const float* src = x1 + (size_t)o * 147456 + i * 384 + j0;
  uint_t w0 = 0, w1 = 0;
#pragma unroll
  for (int k = 0; k < 4; ++k) {
    w0 |= f32_to_e4m3((j0 + k     <= 372) ? src[k]     : 0.f) << (8 * k);
    w1 |= f32_to_e4m3((j0 + 4 + k <= 372) ? src[4 + k] : 0.f) << (8 * k);
  }
  uint2_t u = {w0, w1};
  const int off = (xb >> 3) * 2048 + ((xb >> 1) & 1) * 1024 +
                  ((xb >> 2) & 1) * 512 + o * 16 + (xb & 1) * 8;
  *(uint2_t*)(filtb + (size_t)rowr * FILTB_ROW_B + off) = u;
}

// ---------------------------------------------------------------------------
// Stage 2: correlation via MX-scaled 32x32x64 fp8 MFMA (unit scales).
//   out[o,c,dy,dx] = sum_{y,x} filt[o][y-dy_a][x] * prev[c][y+6*dy_b][x+dx]
//   M=192=(dy_a 6)x(o 32); N=96: n = dyb*24+dx (dx 0..22, 23=pad);
//   K=(y, x): 6 kt64 steps of 64 per y, split across 2 waves.
// Block 768 thr = 12 waves = 2 channel groups x 6 waves. Within a group,
// wave gw = (pair p 0..2) x (K-half kh 0..1): computes dy_a in {2p,2p+1}
// for kt in {3kh..3kh+2}, all 3 nt. One Bf read feeds TWO MFMAs -> B LDS
// reads halve vs R18. Both K-half waves atomicAdd partials (epilogue
// already sums over chunks). SIMD placement 3,3,3,3 -> balanced pipes.
// A: 8-slot LDS ring shared by both groups; rows y..y+5 live; wave reads
// slots (y+5-dy_a)&7. B: per-group double-buffered shifted-copy image.
// Operand map (32x32x64 f8f6f4): m/n = lane&31, k = (lane>>5)*32 + j.
// C/D map: col = lane&31, row = (reg&3)+8*(reg>>2)+4*(lane>>5).
// ---------------------------------------------------------------------------
__global__ __launch_bounds__(768, 3) void corr_kernel(
    const uchar_t* __restrict__ filtb, const uchar_t* __restrict__ prevb,
    float* __restrict__ x2)
{
  extern __shared__ uchar_t smem[];          // [A ring 98304][B 55296]

  const int tid = threadIdx.x;
  const int lane = tid & 63;
  const int wv = tid >> 6;               // 0..11
  const int cg = (wv >= 6) ? 1 : 0;      // channel sub-group
  const int gw = wv - 6 * cg;            // 0..5
  const int p = gw >> 1;                 // dy_a pair 0..2
  const int kh = gw & 1;                 // K-half 0..1
  const int kg = lane >> 5;              // k-group 0..1
  const int nn = lane & 31;              // n (or o) within tile

  const int chpair = blockIdx.x / NCHUNKS;     // 0..15
  const int chunk = blockIdx.x % NCHUNKS;      // 0..15; %8 == XCD
  const int ch = 2 * chpair + cg;              // 0..31
  const int y0 = (chunk * YMAX) / NCHUNKS;     // balanced 22-23 y-steps
  const int y1 = ((chunk + 1) * YMAX) / NCHUNKS;

  uint_t* const sBg = (uint_t*)(smem + SA_BYTES) + cg * (2 * (SB_ROW_B / 4));

  // Per-lane B window byte offsets within a y-row image (32B contiguous,
  // 8B-aligned): copy s = dx&7 is the row shifted by s bytes. Base kt
  // offset kh*192 folded in (3 kt x 64B per K-half).
  int boffB[3];
#pragma unroll
  for (int nt = 0; nt < 3; ++nt) {
    const int n = nt * 32 + nn;          // 0..95
    const int dyb = n / 24;
    const int dxr = n - 24 * dyb;
    const int dx = (dxr < 23) ? dxr : 22;      // pad lane reads valid data
    const int s = dx & 7;
    boffB[nt] = dyb * SB_DYB_B + s * SB_COPY_B + (dx >> 3) * 8 + kg * 32
              + kh * 192;
  }

  // B staging per group: 104 tasks (dyb = t/26, 16B group g = t%26).
  const int tl = tid - cg * 384;               // 0..383 within group
  const bool st_act = (tl < 104);
  const int sdyb = st_act ? (tl / 26) : 0;
  const int sg = tl - 26 * (st_act ? (tl / 26) : 0);
  const uchar_t* srcbase = prevb + ((size_t)(ch * 385 + 6 * sdyb)) * PREVB_STRIDE;
  const int dstoff = sdyb * (SB_DYB_B / 4) + 4 * sg;   // word offset in buffer

  uint_t st0 = 0, st1 = 0, st2 = 0, st3 = 0, st4 = 0, st5 = 0;

  auto load_st = [&](int yy) {
    const uint_t* sw = (const uint_t*)(srcbase + (size_t)yy * PREVB_STRIDE) + 4 * sg;
    const uint4_t lo = *(const uint4_t*)(sw);
    const uint2_t hi = *(const uint2_t*)(sw + 4);
    st0 = lo.x; st1 = lo.y; st2 = lo.z; st3 = lo.w; st4 = hi.x; st5 = hi.y;
  };

  auto write_shift = [&](int buf) {
    uint_t* dst = sBg + buf * (SB_ROW_B / 4) + dstoff;
    const uint_t wd[6] = {st0, st1, st2, st3, st4, st5};
#pragma unroll
    for (int s = 0; s < 8; ++s) {
      const int off = s >> 2;
      const int b = (s & 3) * 8;
      uint4_t v;
      if (b == 0) {
        v = uint4_t{wd[off], wd[off + 1], wd[off + 2], wd[off + 3]};
      } else {
        v = uint4_t{(wd[off]     >> b) | (wd[off + 1] << (32 - b)),
                    (wd[off + 1] >> b) | (wd[off + 2] << (32 - b)),
                    (wd[off + 2] >> b) | (wd[off + 3] << (32 - b)),
                    (wd[off + 3] >> b) | (wd[off + 4] << (32 - b))};
      }
      *(uint4_t*)(dst + s * (SB_COPY_B / 4)) = v;
    }
  };

  f32x16 acc[2][3];
#pragma unroll
  for (int m = 0; m < 2; ++m)
#pragma unroll
    for (int nt = 0; nt < 3; ++nt)
#pragma unroll
      for (int r = 0; r < 16; ++r) acc[m][nt][r] = 0.f;

  // ---- Prologue ----
  // A: stage 6 filt rows y0..y0+5 into ring slots (row&7); 768 thr x 16B.
  {
    uint4_t pv[6];
#pragma unroll
    for (int r6 = 0; r6 < 6; ++r6)
      pv[r6] = *(const uint4_t*)(filtb + (size_t)(y0 + r6) * FILTB_ROW_B + tid * 16);
#pragma unroll
    for (int r6 = 0; r6 < 6; ++r6)
      *(uint4_t*)(smem + ((y0 + r6) & 7) * FILTB_ROW_B + tid * 16) = pv[r6];
  }
  // B: stage y0 into buf 0; preload y0+1 into regs.
  if (st_act) {
    load_st(y0);
    write_shift(0);
    if (y0 + 1 < y1) load_st(y0 + 1);
  }

  __syncthreads();                       // A rows y0..y0+5 + B buf0 staged

  for (int y = y0; y < y1; ++y) {
    const int pb = (y - y0) & 1;         // B buffer being read this iteration

    // A: issue global load of filt row y+6 (used from iteration y+1 on;
    // written to LDS after this K-loop -> a full K-loop of latency cover).
    const bool a_act = (y + 6 <= y1 + 4);
    uint4_t aval;
    if (a_act)
      aval = *(const uint4_t*)(filtb + (size_t)(y + 6) * FILTB_ROW_B + tid * 16);

    // B: stage y+1 into the other buffer; prefetch y+2 into regs.
    if (st_act && y + 1 < y1) write_shift(pb ^ 1);
    if (st_act && y + 2 < y1) load_st(y + 2);

    const char* sBrd = (const char*)sBg + pb * SB_ROW_B;
    // A rows for this wave's two dy_a values (2p and 2p+1), at this wave's
    // K-half offset (kh*3 kt steps x 2048B).
    const char* aRow0 = (const char*)smem +
        ((y + 5 - 2 * p) & 7) * FILTB_ROW_B + kh * 6144 + kg * 512 + nn * 16;
    const char* aRow1 = (const char*)smem +
        ((y + 4 - 2 * p) & 7) * FILTB_ROW_B + kh * 6144 + kg * 512 + nn * 16;

    // K-loop: 3 kt64 steps (this wave's half), pure LDS, minimal live set.
#pragma unroll 1
    for (int kt = 0; kt < 3; ++kt) {
      const uint4_t a00 = *(const uint4_t*)(aRow0 + (kt << 11));
      const uint4_t a01 = *(const uint4_t*)(aRow0 + (kt << 11) + 1024);
      const int8v Af0 = {(int)a00.x, (int)a00.y, (int)a00.z, (int)a00.w,
                         (int)a01.x, (int)a01.y, (int)a01.z, (int)a01.w};
      const uint4_t a10 = *(const uint4_t*)(aRow1 + (kt << 11));
      const uint4_t a11 = *(const uint4_t*)(aRow1 + (kt << 11) + 1024);
      const int8v Af1 = {(int)a10.x, (int)a10.y, (int)a10.z, (int)a10.w,
                         (int)a11.x, (int)a11.y, (int)a11.z, (int)a11.w};
#pragma unroll
      for (int nt = 0; nt < 3; ++nt) {
        const char* bp = sBrd + boffB[nt] + (kt << 6);
        const uint2_t b0 = *(const uint2_t*)(bp);
        const uint2_t b1 = *(const uint2_t*)(bp + 8);
        const uint2_t b2 = *(const uint2_t*)(bp + 16);
        const uint2_t b3 = *(const uint2_t*)(bp + 24);
        const int8v Bf = {(int)b0.x, (int)b0.y, (int)b1.x, (int)b1.y,
                          (int)b2.x, (int)b2.y, (int)b3.x, (int)b3.y};
        acc[0][nt] = __builtin_amdgcn_mfma_scale_f32_32x32x64_f8f6f4(
            Af0, Bf, acc[0][nt], 0, 0, 0, 0x7F7F7F7F, 0, 0x7F7F7F7F);
        acc[1][nt] = __builtin_amdgcn_mfma_scale_f32_32x32x64_f8f6f4(
            Af1, Bf, acc[1][nt], 0, 0, 0, 0x7F7F7F7F, 0, 0x7F7F7F7F);
      }
    }

    // A: write staged row into ring slot (y+6)&7 — disjoint from slots
    // {y..y+5}&7 still being read by other waves; safe without a barrier.
    if (a_act)
      *(uint4_t*)(smem + ((y + 6) & 7) * FILTB_ROW_B + tid * 16) = aval;

    __syncthreads();                     // A row y+6 + B buf y+1 visible
  }

  // Epilogue: scale partials, atomically accumulate into x2[o][c][dy][dx].
  // Both K-half waves contribute; atomics sum them like chunk partials.
#pragma unroll
  for (int m = 0; m < 2; ++m) {
    const int dya = 2 * p + m;
#pragma unroll
    for (int nt = 0; nt < 3; ++nt) {
      const int n = nt * 32 + nn;
      const int dyb = n / 24;
      const int dxr = n - 24 * dyb;
      if (dxr < 23) {
        const int dy = dya + 6 * dyb;
        if (dy <= 22) {
#pragma unroll
          for (int r = 0; r < 16; ++r) {
            const int o = (r & 3) + 8 * (r >> 2) + 4 * kg;   // C/D row
            atomicAdd(&x2[((o * 32 + ch) * 23 + dy) * 23 + dxr],
                      acc[m][nt][r] * INV_AREA);
          }
        }
      }
    }
  }
}

// ---------------------------------------------------------------------------
extern "C" void kernel_launch(void* const* d_in, const int* in_sizes, int n_in,
                              void* d_out, int out_size, void* d_ws, size_t ws_size,
                              hipStream_t stream)
{
  const float* x     = (const float*)d_in[0];   // [3][394][394]
  const float* xprev = (const float*)d_in[1];
  const float* ft    = (const float*)d_in[2];   // [16][3][11][11]
  const float* fn    = (const float*)d_in[3];   // [16][1][11][11]
  float* out = (float*)d_out;

  uchar_t* filtb = (uchar_t*)d_ws;
  uchar_t* prevb = filtb + FILTB_BYTES;
  float* fT2 = (float*)(prevb + PREVB_BYTES);

  static bool attr_set = false;
  if (!attr_set) {
    (void)hipFuncSetAttribute((const void*)corr_kernel,
        hipFuncAttributeMaxDynamicSharedMemorySize, SMEM_TOTAL);
    attr_set = true;
  }

  // Zero packed buffers (zero padding) and the x2 accumulator.
  hipMemsetAsync(d_ws, 0, ZERO_BYTES, stream);
  hipMemsetAsync(out + X1_N, 0, (size_t)X2_N * sizeof(float), stream);

  prep_kernel<<<dim3((FT2_ELEMS + 255) / 256), 256, 0, stream>>>(ft, fn, fT2);
  feat_kernel<<<dim3(24, 48, 2), 128, 0, stream>>>(x, xprev, fT2, out, prevb);
  pack_kernel<<<dim3((362 * 46 * 32 + 255) / 256), 256, 0, stream>>>(out, filtb);
  corr_kernel<<<dim3(16 * NCHUNKS), 768, SMEM_TOTAL, stream>>>(
      filtb, prevb, out + X1_N);
}

// Round 10
// 276.274 us; speedup vs baseline: 1.1693x; 1.1693x over previous
//
#include <hip/hip_runtime.h>
#include <hip/hip_bf16.h>

// Net_22625887715641: fused conv-feats + channel-normalize + 32x32 normalized
// cross-correlation (23x23 shifts, 362x362 templates).
//
// R20 vs R19 (corr 169.6us REGRESSION) / R17 (corr 125.4us, best):
//  R19 post-mortem: acc[2][3]=96 AGPR + 80 VGPR = 176 regs > 170 -> lost
//  3-waves/SIMD residency (MfmaUtil 19) + doubled epilogue atomics. The
//  B-halving itself worked (conflicts 7.05M->3.66M) but regs killed it.
//  -> revert corr compute to R17 exactly (acc 48, 0-deep loads, unroll 1).
//  R17's remaining structural defect: waves 0-1 of each group run staging
//  + full K-loop -> they ARE the barrier critical path; and 12 identical-
//  phase waves collide on LDS/MFMA phases.
//  - Producer-consumer: block = 1024 thr = 16 waves. wv 0-11 = compute
//    (2 ch-groups x 6 dy_a, R17 K-loop verbatim, no staging). wv 12-15 =
//    producers, one per SIMD (round-robin wv%4): ALL staging (A row y+6
//    48B/thr -> ring slot (y+6)&7; B row y+1 -> 8 shifted copies, 104
//    tasks per group from 2 waves). Producers cover global latency inside
//    the K-loop window; barrier structure unchanged (disjoint slots).
//  - Per SIMD: 3 compute + 1 producer = 4 waves (128-reg budget; consumer
//    ~104). Compute balance stays 3,3,3,3.
//  - feat/pack/prep unchanged.

typedef unsigned short ushort_t;
typedef unsigned int uint_t;
typedef unsigned char uchar_t;
typedef __attribute__((ext_vector_type(4))) float f32x4;
typedef __attribute__((ext_vector_type(16))) float f32x16;
typedef __attribute__((ext_vector_type(4))) uint_t uint4_t;
typedef __attribute__((ext_vector_type(2))) uint_t uint2_t;
typedef __attribute__((ext_vector_type(8))) int int8v;

#define EPSF 2.2204460492503131e-16f
#define X1_N (32*384*384)
#define X2_N (32*32*23*23)

// filtb: fp8 [372 rows][kt64 6][h 2][kg 2][o 32][16B]; row = yf+5
#define FILTB_ROW_B 12288
#define FILTB_BYTES (372*48*32*8)
// prevb: fp8 [32 c][385 rows][432 x]; data rows 0..383 cols 0..383; zeros else
#define PREVB_STRIDE 432
#define PREVB_BYTES (32*385*PREVB_STRIDE)
#define ZERO_BYTES ((size_t)FILTB_BYTES + PREVB_BYTES)
// fT2: fp32 [16 chp][45 rows][12] after prevb
#define FT2_ELEMS (16*45*12)

#define YMAX 367            // y-steps 0..366
#define NCHUNKS 16          // 16 chpairs x 16 chunks = 256 blocks = 1/CU
#define INV_AREA (1.0f/131044.0f)

// One prev y-row image in LDS: [dyb 4][copy 8][432]; copy stride 432
#define SB_COPY_B 432
#define SB_DYB_B  (8*SB_COPY_B)     // 3456
#define SB_ROW_B  (4*SB_DYB_B)      // 13824 B per y-row image
#define SB_BYTES  (2*2*SB_ROW_B)    // [group][buf] = 55296 B

// A-ring: 8 slots x one filtb row
#define SA_BYTES  (8*FILTB_ROW_B)   // 98304 B
#define SMEM_TOTAL (SA_BYTES + SB_BYTES)   // 153600 B

// ---------------------------------------------------------------------------
// fp32 -> fp8 e4m3 (OCP), RNE, input assumed in [0, 448).
// ---------------------------------------------------------------------------
__device__ __forceinline__ uint_t f32_to_e4m3(float f) {
  if (f < 0.015625f)                         // subnormal: m * 2^-9
    return (uint_t)__float2int_rn(f * 512.0f);
  uint_t b = __builtin_bit_cast(uint_t, f);
  int e = (int)(b >> 23) - 127;
  uint_t m = b & 0x7FFFFFu;
  uint_t keep = m >> 20;
  uint_t rest = m & 0xFFFFFu;
  keep += (rest > 0x80000u) || (rest == 0x80000u && (keep & 1u));
  if (keep == 8u) { keep = 0u; e += 1; }
  if (e > 8) return 0x7Eu;                   // saturate 448
  return (uint_t)(((e + 7) << 3) | keep);
}

// ---------------------------------------------------------------------------
// Prep: pack filters to [chp][45][12] (rows 16B-aligned, b-contiguous).
// ---------------------------------------------------------------------------
__global__ void prep_kernel(const float* __restrict__ ft, const float* __restrict__ fn,
                            float* __restrict__ fT2)
{
  const int e = blockIdx.x * 256 + threadIdx.x;
  if (e < FT2_ELEMS) {
    const int chp = e / 540;
    const int rem = e - chp * 540;
    const int row = rem / 12;
    const int j = rem - row * 12;
    float v = 0.f;
    if (j < 11) {
      if (row < 33)      v = ft[chp * 363 + row * 11 + j];        // row = t*11+a
      else if (row < 44) v = fn[chp * 121 + (row - 33) * 11 + j]; // row-33 = a
    }
    fT2[e] = v;
  }
}

// ---------------------------------------------------------------------------
// Stage 1: thread = (ch-pair chp) x (16-px row). Block 128 = 8 rows x 16 chp.
// mode 0: x -> x1 (fp32, LDS-transposed coalesced stores).
// mode 1: xprev -> prevb (fp8 e4m3).
// ---------------------------------------------------------------------------
__global__ __launch_bounds__(128, 4) void feat_kernel(
    const float* __restrict__ xcur, const float* __restrict__ xprev,
    const float* __restrict__ fT2,
    float* __restrict__ out_x1, uchar_t* __restrict__ prevb)
{
  __shared__ float sPx[3 * 18 * 28];
  __shared__ float sOut[32][9][20];    // [ch][r pad 9][px pad 20] bank-safe
  const int tid = threadIdx.x;
  const int chp = tid & 15;
  const int r = tid >> 4;              // 0..7
  const int j0 = blockIdx.x * 16;
  const int i0 = blockIdx.y * 8;
  const int i = i0 + r;
  const int mode = blockIdx.z;
  const float* __restrict__ xin = mode ? xprev : xcur;

  for (int e = tid; e < 3 * 18 * 26; e += 128) {
    const int t = e / 468;
    const int rem = e - t * 468;
    const int ri = rem / 26;
    const int ci = rem - ri * 26;
    sPx[(t * 18 + ri) * 28 + ci] = xin[((size_t)t * 394 + i0 + ri) * 394 + j0 + ci];
  }
  __syncthreads();

  const float* __restrict__ fbase = fT2 + chp * 540;

  float accT[16], accN[16];
#pragma unroll
  for (int p = 0; p < 16; ++p) { accT[p] = 0.f; accN[p] = 0.f; }

#pragma unroll
  for (int t = 0; t < 3; ++t) {
    for (int a = 0; a < 11; ++a) {
      const float* row = &sPx[(t * 18 + r + a) * 28];
      float wv[26];
#pragma unroll
      for (int k = 0; k < 6; ++k) {
        const f32x4 q = *(const f32x4*)(row + 4 * k);
        wv[4 * k + 0] = q[0]; wv[4 * k + 1] = q[1];
        wv[4 * k + 2] = q[2]; wv[4 * k + 3] = q[3];
      }
      wv[24] = row[24]; wv[25] = row[25];

      const float* fr = fbase + (t * 11 + a) * 12;
      const f32x4 fq0 = *(const f32x4*)(fr);
      const f32x4 fq1 = *(const f32x4*)(fr + 4);
      const f32x4 fq2 = *(const f32x4*)(fr + 8);
      float fv[12];
#pragma unroll
      for (int k = 0; k < 4; ++k) { fv[k] = fq0[k]; fv[4+k] = fq1[k]; fv[8+k] = fq2[k]; }
      float fv2[12];
      if (t == 2) {
        const float* fr2 = fbase + (33 + a) * 12;
        const f32x4 g0 = *(const f32x4*)(fr2);
        const f32x4 g1 = *(const f32x4*)(fr2 + 4);
        const f32x4 g2 = *(const f32x4*)(fr2 + 8);
#pragma unroll
        for (int k = 0; k < 4; ++k) { fv2[k] = g0[k]; fv2[4+k] = g1[k]; fv2[8+k] = g2[k]; }
      }

#pragma unroll
      for (int b = 0; b < 11; ++b) {
        const float fT = fv[b];
#pragma unroll
        for (int p = 0; p < 16; ++p) accT[p] = fmaf(wv[b + p], fT, accT[p]);
        if (t == 2) {
          const float fN = fv2[b];
#pragma unroll
          for (int p = 0; p < 16; ++p) accN[p] = fmaf(wv[b + p], fN, accN[p]);
        }
      }
    }
  }

  float o0[16], o1[16];
#pragma unroll
  for (int p = 0; p < 16; ++p) {
    const float vT = fmaxf(accT[p], 0.f) * 0.5f;   // temp: relu(conv)/2
    const float vN = fmaxf(accN[p], 0.f);
    float s = vT + vN;
    s += __shfl_xor(s, 1);  s += __shfl_xor(s, 2);
    s += __shfl_xor(s, 4);  s += __shfl_xor(s, 8);
    const float inv = 1.f / (s + EPSF);
    o0[p] = vT * inv;
    o1[p] = vN * inv;
  }

  if (mode == 0) {
    // Stage to LDS, then write 64B-contiguous segments (4 lanes per line).
#pragma unroll
    for (int p = 0; p < 16; ++p) {
      sOut[chp][r][p] = o0[p];
      sOut[chp + 16][r][p] = o1[p];
    }
    __syncthreads();
#pragma unroll
    for (int it = 0; it < 8; ++it) {
      const int idx = it * 128 + tid;        // 0..1023 = 32ch x 8r x 4seg
      const int seg = idx & 3;
      const int rr = (idx >> 2) & 7;
      const int chn = idx >> 5;
      const f32x4 v = {sOut[chn][rr][4 * seg], sOut[chn][rr][4 * seg + 1],
                       sOut[chn][rr][4 * seg + 2], sOut[chn][rr][4 * seg + 3]};
      *(f32x4*)(out_x1 + (size_t)chn * 147456 + (i0 + rr) * 384 + j0 + 4 * seg) = v;
    }
  } else {
    uint4_t u0, u1;
#pragma unroll
    for (int q = 0; q < 4; ++q) {
      u0[q] = f32_to_e4m3(o0[4*q]) | (f32_to_e4m3(o0[4*q+1]) << 8) |
              (f32_to_e4m3(o0[4*q+2]) << 16) | (f32_to_e4m3(o0[4*q+3]) << 24);
      u1[q] = f32_to_e4m3(o1[4*q]) | (f32_to_e4m3(o1[4*q+1]) << 8) |
              (f32_to_e4m3(o1[4*q+2]) << 16) | (f32_to_e4m3(o1[4*q+3]) << 24);
    }
    *(uint4_t*)(prevb + ((size_t)chp * 385 + i) * PREVB_STRIDE + j0) = u0;
    *(uint4_t*)(prevb + ((size_t)(chp + 16) * 385 + i) * PREVB_STRIDE + j0) = u1;
  }
}

// ---------------------------------------------------------------------------
// Pack x1 (fp32, cropped) into filtb fp8 MFMA-A layout; coalesced 8B writes.
// Layout per row: [kt64 6][h 2][kg 2][o 32][16B]; element k = xb*8+j:
// kt64 = xb>>3, kg = (xb>>2)&1, h = (xb>>1)&1, byte16 = (xb&1)*8 + j.
// ---------------------------------------------------------------------------
__global__ __launch_bounds__(256) void pack_kernel(
    const float* __restrict__ x1, uchar_t* __restrict__ filtb)
{
  const int e = blockIdx.x * 256 + threadIdx.x;
  if (e >= 362 * 46 * 32) return;
  const int o = e & 31;
  const int q = e >> 5;
  const int xb = q % 46;
  const int rowr = q / 46 + 5;          // 5..366
  const int i = rowr + 6;               // 11..372
  const int j0 = 11 + xb * 8;
  const float* src = x1 + (size_t)o * 147456 + i * 384 + j0;
  uint_t w0 = 0, w1 = 0;
#pragma unroll
  for (int k = 0; k < 4; ++k) {
    w0 |= f32_to_e4m3((j0 + k     <= 372) ? src[k]     : 0.f) << (8 * k);
    w1 |= f32_to_e4m3((j0 + 4 + k <= 372) ? src[4 + k] : 0.f) << (8 * k);
  }
  uint2_t u = {w0, w1};
  const int off = (xb >> 3) * 2048 + ((xb >> 1) & 1) * 1024 +
                  ((xb >> 2) & 1) * 512 + o * 16 + (xb & 1) * 8;
  *(uint2_t*)(filtb + (size_t)rowr * FILTB_ROW_B + off) = u;
}

// ---------------------------------------------------------------------------
// Stage 2: correlation via MX-scaled 32x32x64 fp8 MFMA (unit scales).
//   out[o,c,dy,dx] = sum_{y,x} filt[o][y-dy_a][x] * prev[c][y+6*dy_b][x+dx]
//   M=192=(dy_a 6)x(o 32); N=96: n = dyb*24+dx (dx 0..22, 23=pad);
//   K=(y, x): 6 kt64 steps of 64 per y.
// Block 1024 thr = 16 waves, producer-consumer:
//   wv 0-11 = compute: 2 channel groups x 6 dy_a waves (R17 K-loop, pure
//     LDS, 0-deep loads, unroll 1). Round-robin placement -> 3 comp/SIMD.
//   wv 12-15 = producers, one per SIMD: ALL staging. wv12,13 -> group 0,
//     wv14,15 -> group 1 for B (104 tasks per group); all 4 waves (ptid
//     0..255, 48B each) for the shared A row.
// A: 8-slot LDS ring shared by both groups; rows y..y+5 live; producers
// write slot (y+6)&7 (disjoint). B: per-group double-buffered shifted-copy
// image; producers write buf pb^1 while consumers read pb. One barrier/y.
// Operand map (32x32x64 f8f6f4): m/n = lane&31, k = (lane>>5)*32 + j.
// C/D map: col = lane&31, row = (reg&3)+8*(reg>>2)+4*(lane>>5).
// ---------------------------------------------------------------------------
__global__ __launch_bounds__(1024, 4) void corr_kernel(
    const uchar_t* __restrict__ filtb, const uchar_t* __restrict__ prevb,
    float* __restrict__ x2)
{
  extern __shared__ uchar_t smem[];          // [A ring 98304][B 55296]

  const int tid = threadIdx.x;
  const int lane = tid & 63;
  const int wv = tid >> 6;               // 0..15
  const bool is_comp = (wv < 12);
  const int pw = wv - 12;                // producers 0..3 (neg for compute)
  const int cgu = is_comp ? ((wv >= 6) ? 1 : 0) : (pw >> 1);  // channel group
  const int w = is_comp ? (wv - 6 * ((wv >= 6) ? 1 : 0)) : 0; // dy_a
  const int kg = lane >> 5;              // k-group 0..1
  const int nn = lane & 31;              // n (or o) within tile

  const int chpair = blockIdx.x / NCHUNKS;     // 0..15
  const int chunk = blockIdx.x % NCHUNKS;      // 0..15; %8 == XCD
  const int ch = 2 * chpair + cgu;             // 0..31
  const int y0 = (chunk * YMAX) / NCHUNKS;     // balanced 22-23 y-steps
  const int y1 = ((chunk + 1) * YMAX) / NCHUNKS;

  uint_t* const sBg = (uint_t*)(smem + SA_BYTES) + cgu * (2 * (SB_ROW_B / 4));

  // Per-lane B window byte offsets within a y-row image (32B contiguous,
  // 8B-aligned): copy s = dx&7 is the row shifted by s bytes.
  int boffB[3];
#pragma unroll
  for (int nt = 0; nt < 3; ++nt) {
    const int n = nt * 32 + nn;          // 0..95
    const int dyb = n / 24;
    const int dxr = n - 24 * dyb;
    const int dx = (dxr < 23) ? dxr : 22;      // pad lane reads valid data
    const int s = dx & 7;
    boffB[nt] = dyb * SB_DYB_B + s * SB_COPY_B + (dx >> 3) * 8 + kg * 32;
  }

  // Producer B staging: 104 tasks per group from 2 waves (128 threads).
  const int tl = is_comp ? 0 : ((pw & 1) * 64 + lane);   // 0..127
  const bool b_act = (!is_comp) && (tl < 104);
  const int sdyb = b_act ? (tl / 26) : 0;
  const int sg = tl - 26 * (b_act ? (tl / 26) : 0);
  const uchar_t* srcbase = prevb + ((size_t)(ch * 385 + 6 * sdyb)) * PREVB_STRIDE;
  const int dstoff = sdyb * (SB_DYB_B / 4) + 4 * sg;     // word offset in buf

  // B: load row yy (24B window), expand to 8 byte-shifted copies in buf.
  auto stage_B = [&](int yy, int buf) {
    const uint_t* sw = (const uint_t*)(srcbase + (size_t)yy * PREVB_STRIDE) + 4 * sg;
    const uint4_t lo = *(const uint4_t*)(sw);
    const uint2_t hi = *(const uint2_t*)(sw + 4);
    const uint_t wd[6] = {lo.x, lo.y, lo.z, lo.w, hi.x, hi.y};
    uint_t* dst = sBg + buf * (SB_ROW_B / 4) + dstoff;
#pragma unroll
    for (int s = 0; s < 8; ++s) {
      const int off = s >> 2;
      const int b = (s & 3) * 8;
      uint4_t v;
      if (b == 0) {
        v = uint4_t{wd[off], wd[off + 1], wd[off + 2], wd[off + 3]};
      } else {
        v = uint4_t{(wd[off]     >> b) | (wd[off + 1] << (32 - b)),
                    (wd[off + 1] >> b) | (wd[off + 2] << (32 - b)),
                    (wd[off + 2] >> b) | (wd[off + 3] << (32 - b)),
                    (wd[off + 3] >> b) | (wd[off + 4] << (32 - b))};
      }
      *(uint4_t*)(dst + s * (SB_COPY_B / 4)) = v;
    }
  };

  // A: producers (ptid 0..255) copy one filtb row (48B each) into a slot.
  const int ptid = is_comp ? 0 : (pw * 64 + lane);
  auto stage_A = [&](int row, int slot) {
    const uchar_t* src = filtb + (size_t)row * FILTB_ROW_B + ptid * 48;
    uchar_t* dst = smem + (size_t)slot * FILTB_ROW_B + ptid * 48;
    const uint4_t v0 = *(const uint4_t*)(src);
    const uint4_t v1 = *(const uint4_t*)(src + 16);
    const uint4_t v2 = *(const uint4_t*)(src + 32);
    *(uint4_t*)(dst) = v0;
    *(uint4_t*)(dst + 16) = v1;
    *(uint4_t*)(dst + 32) = v2;
  };

  f32x16 acc[3];
#pragma unroll
  for (int nt = 0; nt < 3; ++nt)
#pragma unroll
    for (int r = 0; r < 16; ++r) acc[nt][r] = 0.f;

  // ---- Prologue (producers only) ----
  if (!is_comp) {
#pragma unroll
    for (int r6 = 0; r6 < 6; ++r6)
      stage_A(y0 + r6, (y0 + r6) & 7);
    if (b_act) stage_B(y0, 0);
  }
  __syncthreads();                       // A rows y0..y0+5 + B buf0 staged

  for (int y = y0; y < y1; ++y) {
    const int pb = (y - y0) & 1;         // B buffer consumers read this iter

    if (is_comp) {
      const char* sBrd = (const char*)sBg + pb * SB_ROW_B;
      const char* aRow = (const char*)smem +
          ((y + 5 - w) & 7) * FILTB_ROW_B + kg * 512 + nn * 16;

      // K-loop: 6 kt64 steps, pure LDS, minimal live registers (R17).
#pragma unroll 1
      for (int kt = 0; kt < 6; ++kt) {
        const char* ap = aRow + (kt << 11);
        const uint4_t a0 = *(const uint4_t*)(ap);          // h=0
        const uint4_t a1 = *(const uint4_t*)(ap + 1024);   // h=1
        const int8v Af = {(int)a0.x, (int)a0.y, (int)a0.z, (int)a0.w,
                          (int)a1.x, (int)a1.y, (int)a1.z, (int)a1.w};
#pragma unroll
        for (int nt = 0; nt < 3; ++nt) {
          const char* bp = sBrd + boffB[nt] + (kt << 6);
          const uint2_t b0 = *(const uint2_t*)(bp);
          const uint2_t b1 = *(const uint2_t*)(bp + 8);
          const uint2_t b2 = *(const uint2_t*)(bp + 16);
          const uint2_t b3 = *(const uint2_t*)(bp + 24);
          const int8v Bf = {(int)b0.x, (int)b0.y, (int)b1.x, (int)b1.y,
                            (int)b2.x, (int)b2.y, (int)b3.x, (int)b3.y};
          acc[nt] = __builtin_amdgcn_mfma_scale_f32_32x32x64_f8f6f4(
              Af, Bf, acc[nt], 0, 0,                // fmtA=FP8, fmtB=FP8
              0, 0x7F7F7F7F, 0, 0x7F7F7F7F);        // unit E8M0 scales
        }
      }
    } else {
      // Producers: stage B row y+1 into buf pb^1 (consumers read pb), and
      // A row y+6 into ring slot (y+6)&7 (consumers read slots y..y+5).
      if (b_act && y + 1 < y1) stage_B(y + 1, pb ^ 1);
      if (y + 6 <= y1 + 4) stage_A(y + 6, (y + 6) & 7);
    }

    __syncthreads();                     // A row y+6 + B buf y+1 visible
  }

  // Epilogue: scale partials, atomically accumulate into x2[o][c][dy][dx].
  if (is_comp) {
#pragma unroll
    for (int nt = 0; nt < 3; ++nt) {
      const int n = nt * 32 + nn;
      const int dyb = n / 24;
      const int dxr = n - 24 * dyb;
      if (dxr < 23) {
        const int dy = w + 6 * dyb;
        if (dy <= 22) {
#pragma unroll
          for (int r = 0; r < 16; ++r) {
            const int o = (r & 3) + 8 * (r >> 2) + 4 * kg;   // C/D row
            atomicAdd(&x2[((o * 32 + ch) * 23 + dy) * 23 + dxr],
                      acc[nt][r] * INV_AREA);
          }
        }
      }
    }
  }
}

// ---------------------------------------------------------------------------
extern "C" void kernel_launch(void* const* d_in, const int* in_sizes, int n_in,
                              void* d_out, int out_size, void* d_ws, size_t ws_size,
                              hipStream_t stream)
{
  const float* x     = (const float*)d_in[0];   // [3][394][394]
  const float* xprev = (const float*)d_in[1];
  const float* ft    = (const float*)d_in[2];   // [16][3][11][11]
  const float* fn    = (const float*)d_in[3];   // [16][1][11][11]
  float* out = (float*)d_out;

  uchar_t* filtb = (uchar_t*)d_ws;
  uchar_t* prevb = filtb + FILTB_BYTES;
  float* fT2 = (float*)(prevb + PREVB_BYTES);

  static bool attr_set = false;
  if (!attr_set) {
    (void)hipFuncSetAttribute((const void*)corr_kernel,
        hipFuncAttributeMaxDynamicSharedMemorySize, SMEM_TOTAL);
    attr_set = true;
  }

  // Zero packed buffers (zero padding) and the x2 accumulator.
  hipMemsetAsync(d_ws, 0, ZERO_BYTES, stream);
  hipMemsetAsync(out + X1_N, 0, (size_t)X2_N * sizeof(float), stream);

  prep_kernel<<<dim3((FT2_ELEMS + 255) / 256), 256, 0, stream>>>(ft, fn, fT2);
  feat_kernel<<<dim3(24, 48, 2), 128, 0, stream>>>(x, xprev, fT2, out, prevb);
  pack_kernel<<<dim3((362 * 46 * 32 + 255) / 256), 256, 0, stream>>>(out, filtb);
  corr_kernel<<<dim3(16 * NCHUNKS), 1024, SMEM_TOTAL, stream>>>(
      filtb, prevb, out + X1_N);
}

// Round 11
// 274.994 us; speedup vs baseline: 1.1748x; 1.0047x over previous
//
#include <hip/hip_runtime.h>
#include <hip/hip_bf16.h>

// Net_22625887715641: fused conv-feats + channel-normalize + 32x32 normalized
// cross-correlation (23x23 shifts, 362x362 templates).
//
// R21 vs R20 (corr 124us, MfmaUtil 27%) / R19 (dedup regressed on regs):
//  R20 post-mortem: producers neutral -> staging convoy was not binding.
//  Wall 13k cyc/CU/y = LDS ~9.8k (75% busy; B reads 864 b64 carry a 6x
//  cross-wave redundancy) + MFMA 3.7k, near-additive. R19's B-dedup halved
//  conflicts (7.05M->3.66M) but died on (1) 176 regs > 170 cap and (2)
//  doubled epilogue atomics. R21 = dedup with both fixed:
//  - 12-wave block, 2 groups x (3 dy_a-pairs x 2 K-halves). Wave (p,kh):
//    dy_a {2p,2p+1}, kt {3kh..3kh+2}, all 3 nt; one Bf feeds TWO MFMAs.
//    B reads/CU halve; MFMA count and 3,3,3,3 balance unchanged.
//  - Register diet: B staging STATELESS after the K-loop (no persistent
//    staging regs), tasks spread over waves 0-9 via tid%3 (no convoy);
//    only A's 4-reg aval spans the K-loop (R17-proven). ~48 VGPR + 96
//    AGPR <= 170 at 3 waves/SIMD.
//  - kh partials reduced via LDS (A-ring+B dead post-loop, 147KB reused);
//    only kh=0 waves atomicAdd -> WRITE back to ~49.5MB.
//  - feat/pack/prep unchanged.

typedef unsigned short ushort_t;
typedef unsigned int uint_t;
typedef unsigned char uchar_t;
typedef __attribute__((ext_vector_type(4))) float f32x4;
typedef __attribute__((ext_vector_type(16))) float f32x16;
typedef __attribute__((ext_vector_type(4))) uint_t uint4_t;
typedef __attribute__((ext_vector_type(2))) uint_t uint2_t;
typedef __attribute__((ext_vector_type(8))) int int8v;

#define EPSF 2.2204460492503131e-16f
#define X1_N (32*384*384)
#define X2_N (32*32*23*23)

// filtb: fp8 [372 rows][kt64 6][h 2][kg 2][o 32][16B]; row = yf+5
#define FILTB_ROW_B 12288
#define FILTB_BYTES (372*48*32*8)
// prevb: fp8 [32 c][385 rows][432 x]; data rows 0..383 cols 0..383; zeros else
#define PREVB_STRIDE 432
#define PREVB_BYTES (32*385*PREVB_STRIDE)
#define ZERO_BYTES ((size_t)FILTB_BYTES + PREVB_BYTES)
// fT2: fp32 [16 chp][45 rows][12] after prevb
#define FT2_ELEMS (16*45*12)

#define YMAX 367            // y-steps 0..366
#define NCHUNKS 16          // 16 chpairs x 16 chunks = 256 blocks = 1/CU
#define INV_AREA (1.0f/131044.0f)

// One prev y-row image in LDS: [dyb 4][copy 8][432]; copy stride 432
#define SB_COPY_B 432
#define SB_DYB_B  (8*SB_COPY_B)     // 3456
#define SB_ROW_B  (4*SB_DYB_B)      // 13824 B per y-row image
#define SB_BYTES  (2*2*SB_ROW_B)    // [group][buf] = 55296 B

// A-ring: 8 slots x one filtb row
#define SA_BYTES  (8*FILTB_ROW_B)   // 98304 B
#define SMEM_TOTAL (SA_BYTES + SB_BYTES)   // 153600 B

// ---------------------------------------------------------------------------
// fp32 -> fp8 e4m3 (OCP), RNE, input assumed in [0, 448).
// ---------------------------------------------------------------------------
__device__ __forceinline__ uint_t f32_to_e4m3(float f) {
  if (f < 0.015625f)                         // subnormal: m * 2^-9
    return (uint_t)__float2int_rn(f * 512.0f);
  uint_t b = __builtin_bit_cast(uint_t, f);
  int e = (int)(b >> 23) - 127;
  uint_t m = b & 0x7FFFFFu;
  uint_t keep = m >> 20;
  uint_t rest = m & 0xFFFFFu;
  keep += (rest > 0x80000u) || (rest == 0x80000u && (keep & 1u));
  if (keep == 8u) { keep = 0u; e += 1; }
  if (e > 8) return 0x7Eu;                   // saturate 448
  return (uint_t)(((e + 7) << 3) | keep);
}

// ---------------------------------------------------------------------------
// Prep: pack filters to [chp][45][12] (rows 16B-aligned, b-contiguous).
// ---------------------------------------------------------------------------
__global__ void prep_kernel(const float* __restrict__ ft, const float* __restrict__ fn,
                            float* __restrict__ fT2)
{
  const int e = blockIdx.x * 256 + threadIdx.x;
  if (e < FT2_ELEMS) {
    const int chp = e / 540;
    const int rem = e - chp * 540;
    const int row = rem / 12;
    const int j = rem - row * 12;
    float v = 0.f;
    if (j < 11) {
      if (row < 33)      v = ft[chp * 363 + row * 11 + j];        // row = t*11+a
      else if (row < 44) v = fn[chp * 121 + (row - 33) * 11 + j]; // row-33 = a
    }
    fT2[e] = v;
  }
}

// ---------------------------------------------------------------------------
// Stage 1: thread = (ch-pair chp) x (16-px row). Block 128 = 8 rows x 16 chp.
// mode 0: x -> x1 (fp32, LDS-transposed coalesced stores).
// mode 1: xprev -> prevb (fp8 e4m3).
// ---------------------------------------------------------------------------
__global__ __launch_bounds__(128, 4) void feat_kernel(
    const float* __restrict__ xcur, const float* __restrict__ xprev,
    const float* __restrict__ fT2,
    float* __restrict__ out_x1, uchar_t* __restrict__ prevb)
{
  __shared__ float sPx[3 * 18 * 28];
  __shared__ float sOut[32][9][20];    // [ch][r pad 9][px pad 20] bank-safe
  const int tid = threadIdx.x;
  const int chp = tid & 15;
  const int r = tid >> 4;              // 0..7
  const int j0 = blockIdx.x * 16;
  const int i0 = blockIdx.y * 8;
  const int i = i0 + r;
  const int mode = blockIdx.z;
  const float* __restrict__ xin = mode ? xprev : xcur;

  for (int e = tid; e < 3 * 18 * 26; e += 128) {
    const int t = e / 468;
    const int rem = e - t * 468;
    const int ri = rem / 26;
    const int ci = rem - ri * 26;
    sPx[(t * 18 + ri) * 28 + ci] = xin[((size_t)t * 394 + i0 + ri) * 394 + j0 + ci];
  }
  __syncthreads();

  const float* __restrict__ fbase = fT2 + chp * 540;

  float accT[16], accN[16];
#pragma unroll
  for (int p = 0; p < 16; ++p) { accT[p] = 0.f; accN[p] = 0.f; }

#pragma unroll
  for (int t = 0; t < 3; ++t) {
    for (int a = 0; a < 11; ++a) {
      const float* row = &sPx[(t * 18 + r + a) * 28];
      float wv[26];
#pragma unroll
      for (int k = 0; k < 6; ++k) {
        const f32x4 q = *(const f32x4*)(row + 4 * k);
        wv[4 * k + 0] = q[0]; wv[4 * k + 1] = q[1];
        wv[4 * k + 2] = q[2]; wv[4 * k + 3] = q[3];
      }
      wv[24] = row[24]; wv[25] = row[25];

      const float* fr = fbase + (t * 11 + a) * 12;
      const f32x4 fq0 = *(const f32x4*)(fr);
      const f32x4 fq1 = *(const f32x4*)(fr + 4);
      const f32x4 fq2 = *(const f32x4*)(fr + 8);
      float fv[12];
#pragma unroll
      for (int k = 0; k < 4; ++k) { fv[k] = fq0[k]; fv[4+k] = fq1[k]; fv[8+k] = fq2[k]; }
      float fv2[12];
      if (t == 2) {
        const float* fr2 = fbase + (33 + a) * 12;
        const f32x4 g0 = *(const f32x4*)(fr2);
        const f32x4 g1 = *(const f32x4*)(fr2 + 4);
        const f32x4 g2 = *(const f32x4*)(fr2 + 8);
#pragma unroll
        for (int k = 0; k < 4; ++k) { fv2[k] = g0[k]; fv2[4+k] = g1[k]; fv2[8+k] = g2[k]; }
      }

#pragma unroll
      for (int b = 0; b < 11; ++b) {
        const float fT = fv[b];
#pragma unroll
        for (int p = 0; p < 16; ++p) accT[p] = fmaf(wv[b + p], fT, accT[p]);
        if (t == 2) {
          const float fN = fv2[b];
#pragma unroll
          for (int p = 0; p < 16; ++p) accN[p] = fmaf(wv[b + p], fN, accN[p]);
        }
      }
    }
  }

  float o0[16], o1[16];
#pragma unroll
  for (int p = 0; p < 16; ++p) {
    const float vT = fmaxf(accT[p], 0.f) * 0.5f;   // temp: relu(conv)/2
    const float vN = fmaxf(accN[p], 0.f);
    float s = vT + vN;
    s += __shfl_xor(s, 1);  s += __shfl_xor(s, 2);
    s += __shfl_xor(s, 4);  s += __shfl_xor(s, 8);
    const float inv = 1.f / (s + EPSF);
    o0[p] = vT * inv;
    o1[p] = vN * inv;
  }

  if (mode == 0) {
    // Stage to LDS, then write 64B-contiguous segments (4 lanes per line).
#pragma unroll
    for (int p = 0; p < 16; ++p) {
      sOut[chp][r][p] = o0[p];
      sOut[chp + 16][r][p] = o1[p];
    }
    __syncthreads();
#pragma unroll
    for (int it = 0; it < 8; ++it) {
      const int idx = it * 128 + tid;        // 0..1023 = 32ch x 8r x 4seg
      const int seg = idx & 3;
      const int rr = (idx >> 2) & 7;
      const int chn = idx >> 5;
      const f32x4 v = {sOut[chn][rr][4 * seg], sOut[chn][rr][4 * seg + 1],
                       sOut[chn][rr][4 * seg + 2], sOut[chn][rr][4 * seg + 3]};
      *(f32x4*)(out_x1 + (size_t)chn * 147456 + (i0 + rr) * 384 + j0 + 4 * seg) = v;
    }
  } else {
    uint4_t u0, u1;
#pragma unroll
    for (int q = 0; q < 4; ++q) {
      u0[q] = f32_to_e4m3(o0[4*q]) | (f32_to_e4m3(o0[4*q+1]) << 8) |
              (f32_to_e4m3(o0[4*q+2]) << 16) | (f32_to_e4m3(o0[4*q+3]) << 24);
      u1[q] = f32_to_e4m3(o1[4*q]) | (f32_to_e4m3(o1[4*q+1]) << 8) |
              (f32_to_e4m3(o1[4*q+2]) << 16) | (f32_to_e4m3(o1[4*q+3]) << 24);
    }
    *(uint4_t*)(prevb + ((size_t)chp * 385 + i) * PREVB_STRIDE + j0) = u0;
    *(uint4_t*)(prevb + ((size_t)(chp + 16) * 385 + i) * PREVB_STRIDE + j0) = u1;
  }
}

// ---------------------------------------------------------------------------
// Pack x1 (fp32, cropped) into filtb fp8 MFMA-A layout; coalesced 8B writes.
// Layout per row: [kt64 6][h 2][kg 2][o 32][16B]; element k = xb*8+j:
// kt64 = xb>>3, kg = (xb>>2)&1, h = (xb>>1)&1, byte16 = (xb&1)*8 + j.
// ---------------------------------------------------------------------------
__global__ __launch_bounds__(256) void pack_kernel(
    const float* __restrict__ x1, uchar_t* __restrict__ filtb)
{
  const int e = blockIdx.x * 256 + threadIdx.x;
  if (e >= 362 * 46 * 32) return;
  const int o = e & 31;
  const int q = e >> 5;
  const int xb = q % 46;
  const int rowr = q / 46 + 5;          // 5..366
  const int i = rowr + 6;               // 11..372
  const int j0 = 11 + xb * 8;
  const float* src = x1 + (size_t)o * 147456 + i * 384 + j0;
  uint_t w0 = 0, w1 = 0;
#pragma unroll
  for (int k = 0; k < 4; ++k) {
    w0 |= f32_to_e4m3((j0 + k     <= 372) ? src[k]     : 0.f) << (8 * k);
    w1 |= f32_to_e4m3((j0 + 4 + k <= 372) ? src[4 + k] : 0.f) << (8 * k);
  }
  uint2_t u = {w0, w1};
  const int off = (xb >> 3) * 2048 + ((xb >> 1) & 1) * 1024 +
                  ((xb >> 2) & 1) * 512 + o * 16 + (xb & 1) * 8;
  *(uint2_t*)(filtb + (size_t)rowr * FILTB_ROW_B + off) = u;
}

// ---------------------------------------------------------------------------
// Stage 2: correlation via MX-scaled 32x32x64 fp8 MFMA (unit scales).
//   out[o,c,dy,dx] = sum_{y,x} filt[o][y-dy_a][x] * prev[c][y+6*dy_b][x+dx]
//   M=192=(dy_a 6)x(o 32); N=96: n = dyb*24+dx (dx 0..22, 23=pad);
//   K=(y, x): 6 kt64 steps per y, SPLIT across 2 K-half waves.
// Block 768 thr = 12 waves = 2 channel groups x (3 dy_a-pairs x 2 K-halves).
// Wave (cg, p, kh): dy_a in {2p, 2p+1}, kt64 in {3kh..3kh+2}, all 3 nt;
// one Bf read feeds TWO MFMAs (B LDS reads halve vs 1-dy_a waves). SIMD
// placement 3,3,3,3 -> balanced matrix pipes. acc[2][3] = 96 AGPR; B
// staging stateless after K-loop (no persistent staging regs, tasks spread
// over waves via tid%3); A staging pre-issued (4-reg aval, R17-proven).
// A: 8-slot LDS ring shared by both groups; wave reads slots (y+5-dya)&7.
// B: per-group double-buffered shifted-copy image (copy s = byte-shift s).
// Epilogue: kh=1 partials reduced into kh=0 via LDS (ring dead), single
// atomic set (avoids R19's doubled atomics).
// Operand map (32x32x64 f8f6f4): m/n = lane&31, k = (lane>>5)*32 + j.
// C/D map: col = lane&31, row = (reg&3)+8*(reg>>2)+4*(lane>>5).
// ---------------------------------------------------------------------------
__global__ __launch_bounds__(768, 3) void corr_kernel(
    const uchar_t* __restrict__ filtb, const uchar_t* __restrict__ prevb,
    float* __restrict__ x2)
{
  extern __shared__ uchar_t smem[];          // [A ring 98304][B 55296]

  const int tid = threadIdx.x;
  const int lane = tid & 63;
  const int wv = tid >> 6;               // 0..11
  const int cg = (wv >= 6) ? 1 : 0;      // channel sub-group
  const int gw = wv - 6 * cg;            // 0..5
  const int p = gw >> 1;                 // dy_a pair 0..2
  const int kh = gw & 1;                 // K-half 0..1
  const int kg = lane >> 5;              // k-group 0..1
  const int nn = lane & 31;              // n (or o) within tile

  const int chpair = blockIdx.x / NCHUNKS;     // 0..15
  const int chunk = blockIdx.x % NCHUNKS;      // 0..15; %8 == XCD
  const int ch = 2 * chpair + cg;              // 0..31
  const int y0 = (chunk * YMAX) / NCHUNKS;     // balanced 22-23 y-steps
  const int y1 = ((chunk + 1) * YMAX) / NCHUNKS;

  uint_t* const sBall = (uint_t*)(smem + SA_BYTES);
  uint_t* const sBg = sBall + cg * (2 * (SB_ROW_B / 4));

  // Per-lane B window byte offsets within a y-row image (32B contiguous,
  // 8B-aligned): copy s = dx&7 is the row shifted by s bytes. kh's base kt
  // offset (3 kt x 64B) folded in.
  int boffB[3];
#pragma unroll
  for (int nt = 0; nt < 3; ++nt) {
    const int n = nt * 32 + nn;          // 0..95
    const int dyb = n / 24;
    const int dxr = n - 24 * dyb;
    const int dx = (dxr < 23) ? dxr : 22;      // pad lane reads valid data
    const int s = dx & 7;
    boffB[nt] = dyb * SB_DYB_B + s * SB_COPY_B + (dx >> 3) * 8 + kg * 32
              + kh * 192;
  }

  // B staging: 208 tasks (2 groups x 104) spread across waves via tid%3.
  const int btask = tid / 3;                   // 0..255
  const bool b_act = ((tid % 3) == 0) && (btask < 208);
  const int bgroup = b_act ? (btask / 104) : 0;
  const int t104 = btask - 104 * (b_act ? (btask / 104) : 0);
  const int sdyb = b_act ? (t104 / 26) : 0;
  const int sg = t104 - 26 * (b_act ? (t104 / 26) : 0);
  const uchar_t* srcbase =
      prevb + ((size_t)((2 * chpair + bgroup) * 385 + 6 * sdyb)) * PREVB_STRIDE;
  uint_t* const bdst0 = sBall + bgroup * (2 * (SB_ROW_B / 4)) +
                        sdyb * (SB_DYB_B / 4) + 4 * sg;

  // Stateless B stage: load row yy (24B window), write 8 shifted copies.
  auto stage_B = [&](int yy, int buf) {
    const uint_t* sw = (const uint_t*)(srcbase + (size_t)yy * PREVB_STRIDE) + 4 * sg;
    const uint4_t lo = *(const uint4_t*)(sw);
    const uint2_t hi = *(const uint2_t*)(sw + 4);
    const uint_t wd[6] = {lo.x, lo.y, lo.z, lo.w, hi.x, hi.y};
    uint_t* dst = bdst0 + buf * (SB_ROW_B / 4);
#pragma unroll
    for (int s = 0; s < 8; ++s) {
      const int off = s >> 2;
      const int b = (s & 3) * 8;
      uint4_t v;
      if (b == 0) {
        v = uint4_t{wd[off], wd[off + 1], wd[off + 2], wd[off + 3]};
      } else {
        v = uint4_t{(wd[off]     >> b) | (wd[off + 1] << (32 - b)),
                    (wd[off + 1] >> b) | (wd[off + 2] << (32 - b)),
                    (wd[off + 2] >> b) | (wd[off + 3] << (32 - b)),
                    (wd[off + 3] >> b) | (wd[off + 4] << (32 - b))};
      }
      *(uint4_t*)(dst + s * (SB_COPY_B / 4)) = v;
    }
  };

  f32x16 acc[2][3];
#pragma unroll
  for (int m = 0; m < 2; ++m)
#pragma unroll
    for (int nt = 0; nt < 3; ++nt)
#pragma unroll
      for (int r = 0; r < 16; ++r) acc[m][nt][r] = 0.f;

  // ---- Prologue ----
  // A: stage 6 filt rows y0..y0+5 into ring slots (row&7); 768 thr x 16B.
#pragma unroll 1
  for (int r6 = 0; r6 < 6; ++r6) {
    const uint4_t v = *(const uint4_t*)(
        filtb + (size_t)(y0 + r6) * FILTB_ROW_B + tid * 16);
    *(uint4_t*)(smem + ((y0 + r6) & 7) * FILTB_ROW_B + tid * 16) = v;
  }
  if (b_act) stage_B(y0, 0);
  __syncthreads();                       // A rows y0..y0+5 + B buf0 staged

  for (int y = y0; y < y1; ++y) {
    const int pb = (y - y0) & 1;         // B buffer being read this iteration

    // A: pre-issue global load of filt row y+6 (4 regs across K-loop).
    const bool a_act = (y + 6 <= y1 + 4);
    uint4_t aval;
    if (a_act)
      aval = *(const uint4_t*)(filtb + (size_t)(y + 6) * FILTB_ROW_B + tid * 16);

    const char* sBrd = (const char*)sBg + pb * SB_ROW_B;
    // A rows for this wave's two dy_a values (2p -> row y+5-2p, 2p+1 ->
    // row y+4-2p), at per-lane offset kg*512 + nn*16.
    const char* aRow0 = (const char*)smem +
        ((y + 5 - 2 * p) & 7) * FILTB_ROW_B + kg * 512 + nn * 16;
    const char* aRow1 = (const char*)smem +
        ((y + 4 - 2 * p) & 7) * FILTB_ROW_B + kg * 512 + nn * 16;

    // K-loop: 3 kt64 steps (this wave's K-half), pure LDS, minimal regs.
#pragma unroll 1
    for (int kt = 0; kt < 3; ++kt) {
      const int ktg = kh * 3 + kt;       // global kt64 index
      const uint4_t a00 = *(const uint4_t*)(aRow0 + (ktg << 11));
      const uint4_t a01 = *(const uint4_t*)(aRow0 + (ktg << 11) + 1024);
      const int8v Af0 = {(int)a00.x, (int)a00.y, (int)a00.z, (int)a00.w,
                         (int)a01.x, (int)a01.y, (int)a01.z, (int)a01.w};
      const uint4_t a10 = *(const uint4_t*)(aRow1 + (ktg << 11));
      const uint4_t a11 = *(const uint4_t*)(aRow1 + (ktg << 11) + 1024);
      const int8v Af1 = {(int)a10.x, (int)a10.y, (int)a10.z, (int)a10.w,
                         (int)a11.x, (int)a11.y, (int)a11.z, (int)a11.w};
#pragma unroll
      for (int nt = 0; nt < 3; ++nt) {
        const char* bp = sBrd + boffB[nt] + (kt << 6);
        const uint2_t b0 = *(const uint2_t*)(bp);
        const uint2_t b1 = *(const uint2_t*)(bp + 8);
        const uint2_t b2 = *(const uint2_t*)(bp + 16);
        const uint2_t b3 = *(const uint2_t*)(bp + 24);
        const int8v Bf = {(int)b0.x, (int)b0.y, (int)b1.x, (int)b1.y,
                          (int)b2.x, (int)b2.y, (int)b3.x, (int)b3.y};
        acc[0][nt] = __builtin_amdgcn_mfma_scale_f32_32x32x64_f8f6f4(
            Af0, Bf, acc[0][nt], 0, 0, 0, 0x7F7F7F7F, 0, 0x7F7F7F7F);
        acc[1][nt] = __builtin_amdgcn_mfma_scale_f32_32x32x64_f8f6f4(
            Af1, Bf, acc[1][nt], 0, 0, 0, 0x7F7F7F7F, 0, 0x7F7F7F7F);
      }
    }

    // A: write staged row into ring slot (y+6)&7 (disjoint from y..y+5).
    if (a_act)
      *(uint4_t*)(smem + ((y + 6) & 7) * FILTB_ROW_B + tid * 16) = aval;
    // B: stateless stage of row y+1 into buf pb^1 (readers of pb^1
    // finished at the end-of-(y-1) barrier).
    if (b_act && y + 1 < y1) stage_B(y + 1, pb ^ 1);

    __syncthreads();                     // A row y+6 + B buf y+1 visible
  }

  // ---- Epilogue ----
  // Reduce kh=1 partials into kh=0 via LDS (A-ring + B images are dead).
  // Region r = cg*3+p; block q (0..23) = 64 lanes x 16B; conflict-free.
  {
    uchar_t* const rbase =
        smem + ((size_t)(cg * 3 + p) * 24 * 64 + lane) * 16;
    if (kh == 1) {
      int q = 0;
#pragma unroll
      for (int m = 0; m < 2; ++m)
#pragma unroll
        for (int nt = 0; nt < 3; ++nt)
#pragma unroll
          for (int seg = 0; seg < 4; ++seg) {
            const f32x4 v = {acc[m][nt][4 * seg], acc[m][nt][4 * seg + 1],
                             acc[m][nt][4 * seg + 2], acc[m][nt][4 * seg + 3]};
            *(f32x4*)(rbase + q * 1024) = v;
            ++q;
          }
    }
    __syncthreads();
    if (kh == 0) {
      int q = 0;
#pragma unroll
      for (int m = 0; m < 2; ++m)
#pragma unroll
        for (int nt = 0; nt < 3; ++nt)
#pragma unroll
          for (int seg = 0; seg < 4; ++seg) {
            const f32x4 v = *(const f32x4*)(rbase + q * 1024);
            acc[m][nt][4 * seg] += v[0];
            acc[m][nt][4 * seg + 1] += v[1];
            acc[m][nt][4 * seg + 2] += v[2];
            acc[m][nt][4 * seg + 3] += v[3];
            ++q;
          }
      // Scale and atomically accumulate into x2[o][c][dy][dx].
#pragma unroll
      for (int m = 0; m < 2; ++m) {
        const int dya = 2 * p + m;
#pragma unroll
        for (int nt = 0; nt < 3; ++nt) {
          const int n = nt * 32 + nn;
          const int dyb = n / 24;
          const int dxr = n - 24 * dyb;
          if (dxr < 23) {
            const int dy = dya + 6 * dyb;
            if (dy <= 22) {
#pragma unroll
              for (int r = 0; r < 16; ++r) {
                const int o = (r & 3) + 8 * (r >> 2) + 4 * kg;   // C/D row
                atomicAdd(&x2[((o * 32 + ch) * 23 + dy) * 23 + dxr],
                          acc[m][nt][r] * INV_AREA);
              }
            }
          }
        }
      }
    }
  }
}

// ---------------------------------------------------------------------------
extern "C" void kernel_launch(void* const* d_in, const int* in_sizes, int n_in,
                              void* d_out, int out_size, void* d_ws, size_t ws_size,
                              hipStream_t stream)
{
  const float* x     = (const float*)d_in[0];   // [3][394][394]
  const float* xprev = (const float*)d_in[1];
  const float* ft    = (const float*)d_in[2];   // [16][3][11][11]
  const float* fn    = (const float*)d_in[3];   // [16][1][11][11]
  float* out = (float*)d_out;

  uchar_t* filtb = (uchar_t*)d_ws;
  uchar_t* prevb = filtb + FILTB_BYTES;
  float* fT2 = (float*)(prevb + PREVB_BYTES);

  static bool attr_set = false;
  if (!attr_set) {
    (void)hipFuncSetAttribute((const void*)corr_kernel,
        hipFuncAttributeMaxDynamicSharedMemorySize, SMEM_TOTAL);
    attr_set = true;
  }

  // Zero packed buffers (zero padding) and the x2 accumulator.
  hipMemsetAsync(d_ws, 0, ZERO_BYTES, stream);
  hipMemsetAsync(out + X1_N, 0, (size_t)X2_N * sizeof(float), stream);

  prep_kernel<<<dim3((FT2_ELEMS + 255) / 256), 256, 0, stream>>>(ft, fn, fT2);
  feat_kernel<<<dim3(24, 48, 2), 128, 0, stream>>>(x, xprev, fT2, out, prevb);
  pack_kernel<<<dim3((362 * 46 * 32 + 255) / 256), 256, 0, stream>>>(out, filtb);
  corr_kernel<<<dim3(16 * NCHUNKS), 768, SMEM_TOTAL, stream>>>(
      filtb, prevb, out + X1_N);
}